// Round 10
// baseline (53.843 us; speedup 1.0000x reference)
//
#include <hip/hip_runtime.h>
#include <math.h>

#define NTOK 8192
#define DIMV 512
#define CD 13
#define KSZ 8192
#define NPARTS 512            /* KA blocks == partial-C count               */
#define TPB 16                /* tokens per KA block                        */

/* d_ws layout:
   [0, 16MB)          ws_C   : NPARTS x 8192 partial C
   [+0, +4KB)         ws_pc  : 512 x {cm, pe}
   [+4KB, +1KB)       ws_e   : 256 entropy partials
   [+1KB, +16B)       ws_cnt : done-counter (zeroed by KA each call)        */
#define C_BYTES  ((size_t)NPARTS * KSZ * 4)
#define PC_OFF   C_BYTES
#define E_OFF    (PC_OFF + 4096)
#define CNT_OFF  (E_OFF + 1024)

// ---------------------------------------------------------------------------
// KA: 512 blocks x 256 threads, 16 tokens/block. LDS-free projection:
// each lane reads its 4 w_in rows (208B contiguous, L1-resident) from global.
// 32 lanes/token, f32 partial + f64 5-step butterfly -> indices, h->LDS,
// cm/pe partials, out = sign(h) @ w_out + b_out (w_out from L2),
// factors A[64],B[128] -> LDS, outer product 8x4-tiled -> ws_C.
// ---------------------------------------------------------------------------
__global__ __launch_bounds__(256) void ka_fused(const float* __restrict__ x,
                                                const float* __restrict__ w_in,
                                                const float* __restrict__ b_in,
                                                const float* __restrict__ w_out,
                                                const float* __restrict__ b_out,
                                                float* __restrict__ ws_C,
                                                float* __restrict__ ws_pc,
                                                unsigned int* __restrict__ ws_cnt,
                                                float* __restrict__ outv,
                                                float* __restrict__ out_ind) {
  __shared__ float sh[TPB][CD];                      // h per token
  __shared__ __align__(16) float sA[TPB][64];        // [tok][khi]
  __shared__ __align__(16) float sB[TPB][128];       // [tok][klo]
  __shared__ float s_cm[TPB], s_pe[TPB];
  int t = threadIdx.x;

  if (blockIdx.x == 0 && t == 0) *ws_cnt = 0u;       // reset KB's counter

  int lane = t & 63;
  int wave = t >> 6;          // 0..3
  int l31 = lane & 31;
  int grp = lane >> 5;        // 0..1
  int tok = wave * 4 + grp * 2;                      // wave owns tokens tok, tok+1
  // token assignment: 32-lane group g of wave w handles tokens w*4+g*2 .. +1
  // process 2 tokens per 32-lane group sequentially to cover 16 tokens/block
  const float4* wf4 = (const float4*)w_in;

#pragma unroll
  for (int tt = 0; tt < 2; ++tt) {
    int tk = tok + tt;
    int n = blockIdx.x * TPB + tk;
    const float4* x4 = (const float4*)(x + (size_t)n * DIMV);

    // per-lane f32 partial over 16 elements of d (4 rows of w_in per j)
    float facc[CD];
#pragma unroll
    for (int c = 0; c < CD; ++c) facc[c] = 0.f;
#pragma unroll
    for (int j = 0; j < 4; ++j) {
      int dbase = (l31 + j * 32) * 4;
      float4 xv = x4[l31 + j * 32];
      // w_in rows dbase..dbase+3 = 52 contiguous floats = 13 float4
      float wreg[52];
      const float4* wsrc = wf4 + (size_t)(dbase * CD) / 4;
#pragma unroll
      for (int k = 0; k < 13; ++k) *(float4*)&wreg[k * 4] = wsrc[k];
#pragma unroll
      for (int c = 0; c < CD; ++c) {
        facc[c] += xv.x * wreg[c] + xv.y * wreg[13 + c] +
                   xv.z * wreg[26 + c] + xv.w * wreg[39 + c];
      }
    }
    // f64 butterfly across the 32-lane group
    double acc[CD];
#pragma unroll
    for (int c = 0; c < CD; ++c) {
      double a = (double)facc[c];
      a += __shfl_xor(a, 1, 64);
      a += __shfl_xor(a, 2, 64);
      a += __shfl_xor(a, 4, 64);
      a += __shfl_xor(a, 8, 64);
      a += __shfl_xor(a, 16, 64);
      acc[c] = a + (double)b_in[c];
    }

    // index
    int idx = 0;
#pragma unroll
    for (int c = 0; c < CD; ++c) idx |= (acc[c] > 0.0 ? 1 : 0) << (12 - c);
    if (l31 == 0) out_ind[n] = (float)idx;

    // lane l31 owns channel c==l31: h -> LDS, commit + entropy partials
    float hv = 0.f;
#pragma unroll
    for (int c = 0; c < CD; ++c) if (l31 == c) hv = (float)acc[c];
    float cm = 0.f, pe = 0.f;
    if (l31 < CD) {
      sh[tk][l31] = hv;
      float a = fabsf(hv);
      float d1 = a - 1.f;
      cm = d1 * d1;                     // (h - sign(h))^2 == (|h|-1)^2
      float z = 4.f * a;                // binary entropy of sigmoid(4h)
      float e = expf(-z);
      pe = log1pf(e) + z * e / (1.f + e);
    }
    cm += __shfl_xor(cm, 1, 64); pe += __shfl_xor(pe, 1, 64);
    cm += __shfl_xor(cm, 2, 64); pe += __shfl_xor(pe, 2, 64);
    cm += __shfl_xor(cm, 4, 64); pe += __shfl_xor(pe, 4, 64);
    cm += __shfl_xor(cm, 8, 64); pe += __shfl_xor(pe, 8, 64);
    cm += __shfl_xor(cm, 16, 64); pe += __shfl_xor(pe, 16, 64);
    if (l31 == 0) { s_cm[tk] = cm; s_pe[tk] = pe; }

    // factors for this token (all 32 lanes? need 64 khi -> use both halves)
    // khi = lane (0..63) requires the full wave; defer to after both tokens.
  }

  // ---- out = sign(h) @ w_out + b_out; wave covers its 4 tokens ----
  // (needs idx of 4 tokens: recompute from sh signs — sh holds f32 h)
  __syncthreads();                       // sh complete for all 16 tokens
  {
    int dpos = lane * 4;
    float4 bo0 = *(const float4*)(b_out + dpos);
    float4 bo1 = *(const float4*)(b_out + dpos + 256);
    int base_tok = wave * 4;
    float4 o[4][2];
    int id2[4];
#pragma unroll
    for (int ttk = 0; ttk < 4; ++ttk) {
      o[ttk][0] = bo0; o[ttk][1] = bo1;
      int id = 0;
#pragma unroll
      for (int c = 0; c < CD; ++c)
        id |= (sh[base_tok + ttk][c] > 0.f ? 1 : 0) << (12 - c);
      id2[ttk] = id;
    }
#pragma unroll
    for (int c = 0; c < CD; ++c) {
      const float4 w0 = *(const float4*)&w_out[c * DIMV + dpos];
      const float4 w1 = *(const float4*)&w_out[c * DIMV + dpos + 256];
#pragma unroll
      for (int ttk = 0; ttk < 4; ++ttk) {
        float sgn = ((id2[ttk] >> (12 - c)) & 1) ? 1.f : -1.f;
        o[ttk][0].x = fmaf(sgn, w0.x, o[ttk][0].x);
        o[ttk][0].y = fmaf(sgn, w0.y, o[ttk][0].y);
        o[ttk][0].z = fmaf(sgn, w0.z, o[ttk][0].z);
        o[ttk][0].w = fmaf(sgn, w0.w, o[ttk][0].w);
        o[ttk][1].x = fmaf(sgn, w1.x, o[ttk][1].x);
        o[ttk][1].y = fmaf(sgn, w1.y, o[ttk][1].y);
        o[ttk][1].z = fmaf(sgn, w1.z, o[ttk][1].z);
        o[ttk][1].w = fmaf(sgn, w1.w, o[ttk][1].w);
      }
    }
    int n0 = blockIdx.x * TPB + base_tok;
#pragma unroll
    for (int ttk = 0; ttk < 4; ++ttk) {
      float4* dst = (float4*)(outv + (size_t)(n0 + ttk) * DIMV);
      dst[lane] = o[ttk][0];
      dst[lane + 64] = o[ttk][1];
    }
  }

  if (t == 0) {
    float C = 0.f, P = 0.f;
#pragma unroll
    for (int i = 0; i < TPB; ++i) { C += s_cm[i]; P += s_pe[i]; }
    ws_pc[blockIdx.x * 2] = C;
    ws_pc[blockIdx.x * 2 + 1] = P;
  }

  // ---- factors: wave handles m % 4 == wave; lane = khi ----
  for (int m = wave; m < TPB; m += 4) {
    float p[CD], q[CD];
#pragma unroll
    for (int c = 0; c < CD; ++c) {
      float hvv = sh[m][c];
      float e = expf(-4.f * hvv);
      float r = 1.f / (1.f + e);
      p[c] = r;                         // P(bit c = 1)
      q[c] = e * r;                     // P(bit c = 0)
    }
    float A = ((lane >> 5) & 1) ? p[0] : q[0];
    A *= ((lane >> 4) & 1) ? p[1] : q[1];
    A *= ((lane >> 3) & 1) ? p[2] : q[2];
    A *= ((lane >> 2) & 1) ? p[3] : q[3];
    A *= ((lane >> 1) & 1) ? p[4] : q[4];
    A *= (lane & 1) ? p[5] : q[5];
    sA[m][lane] = A;                    // khi = lane
    float Bb = ((lane >> 5) & 1) ? p[7] : q[7];
    Bb *= ((lane >> 4) & 1) ? p[8] : q[8];
    Bb *= ((lane >> 3) & 1) ? p[9] : q[9];
    Bb *= ((lane >> 2) & 1) ? p[10] : q[10];
    Bb *= ((lane >> 1) & 1) ? p[11] : q[11];
    Bb *= (lane & 1) ? p[12] : q[12];
    sB[m][lane] = q[6] * Bb;            // klo = lane      (bit6 = 0)
    sB[m][64 + lane] = p[6] * Bb;       // klo = lane + 64 (bit6 = 1)
  }
  __syncthreads();

  // ---- outer product, 8x4 tile: thread owns khi in [kh0,kh0+8),
  //      klo in [kl0,kl0+4); per m: 2 b128 (A) + 1 b128 (B) + 32 FMA ----
  int kh0 = (t >> 5) << 3;              // 0,8,..,56
  int kl0 = (t & 31) << 2;              // 0,4,..,124
  float4 acc4[8];
#pragma unroll
  for (int a = 0; a < 8; ++a) acc4[a] = make_float4(0.f, 0.f, 0.f, 0.f);
  for (int m = 0; m < TPB; ++m) {
    float4 bv = *(const float4*)&sB[m][kl0];
    float4 av0 = *(const float4*)&sA[m][kh0];
    float4 av1 = *(const float4*)&sA[m][kh0 + 4];
    float Aa[8] = {av0.x, av0.y, av0.z, av0.w, av1.x, av1.y, av1.z, av1.w};
#pragma unroll
    for (int a = 0; a < 8; ++a) {
      acc4[a].x = fmaf(Aa[a], bv.x, acc4[a].x);
      acc4[a].y = fmaf(Aa[a], bv.y, acc4[a].y);
      acc4[a].z = fmaf(Aa[a], bv.z, acc4[a].z);
      acc4[a].w = fmaf(Aa[a], bv.w, acc4[a].w);
    }
  }
  {
    float* dst = ws_C + (size_t)blockIdx.x * KSZ;
#pragma unroll
    for (int a = 0; a < 8; ++a)
      *(float4*)&dst[(kh0 + a) * 128 + kl0] = acc4[a];   // coalesced rows
  }
}

// ---------------------------------------------------------------------------
// KB: reduce NPARTS partial C's -> 256 entropy partials; the LAST block
// (device atomic counter, zeroed by KA) assembles aux (fixed-order sums ->
// deterministic regardless of which block finishes last).
// ---------------------------------------------------------------------------
__global__ __launch_bounds__(256) void kb_final(const float* __restrict__ ws_C,
                                                const float* __restrict__ ws_pc,
                                                float* __restrict__ ws_e,
                                                unsigned int* __restrict__ ws_cnt,
                                                float* __restrict__ d_aux) {
  __shared__ float red[256];
  __shared__ int s_last;
  int t = threadIdx.x;
  int sl = t & 31, pg = t >> 5;
  int s = blockIdx.x * 32 + sl;
  float a0 = 0.f, a1 = 0.f, a2 = 0.f, a3 = 0.f;
  for (int i = 0; i < 64; i += 4) {
    a0 += ws_C[(size_t)(pg + 8 * (i + 0)) * KSZ + s];
    a1 += ws_C[(size_t)(pg + 8 * (i + 1)) * KSZ + s];
    a2 += ws_C[(size_t)(pg + 8 * (i + 2)) * KSZ + s];
    a3 += ws_C[(size_t)(pg + 8 * (i + 3)) * KSZ + s];
  }
  red[t] = (a0 + a1) + (a2 + a3);
  __syncthreads();
  float contrib = 0.f;
  if (t < 32) {
    float v = red[t];
#pragma unroll
    for (int j = 1; j < 8; ++j) v += red[t + 32 * j];
    float avg = v * (1.f / (float)NTOK);
    contrib = -avg * logf(avg + 1e-5f);
  }
  if (t < 64) {
    contrib += __shfl_xor(contrib, 1, 64);
    contrib += __shfl_xor(contrib, 2, 64);
    contrib += __shfl_xor(contrib, 4, 64);
    contrib += __shfl_xor(contrib, 8, 64);
    contrib += __shfl_xor(contrib, 16, 64);
    if (t == 0) ws_e[blockIdx.x] = contrib;
  }
  if (t == 0) {
    __threadfence();
    unsigned int old = atomicAdd(ws_cnt, 1u);
    s_last = (old == 255u) ? 1 : 0;
  }
  __syncthreads();
  if (s_last) {
    __threadfence();                    // acquire: see all ws_e / ws_pc
    __shared__ float rc[256], rp[256], re[256];
    float cm2 = 0.f, pe2 = 0.f;
    for (int i = t; i < 512; i += 256) {
      cm2 += ws_pc[2 * i];
      pe2 += ws_pc[2 * i + 1];
    }
    rc[t] = cm2; rp[t] = pe2; re[t] = ws_e[t];
    __syncthreads();
    if (t < 64) {
      float C = rc[t] + rc[t + 64] + rc[t + 128] + rc[t + 192];
      float P = rp[t] + rp[t + 64] + rp[t + 128] + rp[t + 192];
      float E = re[t] + re[t + 64] + re[t + 128] + re[t + 192];
      C += __shfl_xor(C, 1, 64); P += __shfl_xor(P, 1, 64); E += __shfl_xor(E, 1, 64);
      C += __shfl_xor(C, 2, 64); P += __shfl_xor(P, 2, 64); E += __shfl_xor(E, 2, 64);
      C += __shfl_xor(C, 4, 64); P += __shfl_xor(P, 4, 64); E += __shfl_xor(E, 4, 64);
      C += __shfl_xor(C, 8, 64); P += __shfl_xor(P, 8, 64); E += __shfl_xor(E, 8, 64);
      C += __shfl_xor(C, 16, 64); P += __shfl_xor(P, 16, 64); E += __shfl_xor(E, 16, 64);
      C += __shfl_xor(C, 32, 64); P += __shfl_xor(P, 32, 64); E += __shfl_xor(E, 32, 64);
      if (t == 0) {
        float commit = C * (1.f / (float)(NTOK * CD));
        float psE = P * (1.f / (float)NTOK);
        d_aux[0] = 0.1f * (psE - E) + 0.25f * commit;
      }
    }
  }
}

extern "C" void kernel_launch(void* const* d_in, const int* in_sizes, int n_in,
                              void* d_out, int out_size, void* d_ws, size_t ws_size,
                              hipStream_t stream) {
  const float* x     = (const float*)d_in[0];
  const float* w_in  = (const float*)d_in[1];
  const float* b_in  = (const float*)d_in[2];
  const float* w_out = (const float*)d_in[3];
  const float* b_out = (const float*)d_in[4];
  // d_in[5] = codebook (unused: codes are the 13-bit sign patterns)

  float* outv = (float*)d_out;                       // [4*2048*512]
  float* ind  = outv + (size_t)NTOK * DIMV;          // [8192] as float
  float* aux  = ind + NTOK;                          // [1]

  float*        ws_C   = (float*)d_ws;
  float*        ws_pc  = (float*)((char*)d_ws + PC_OFF);
  float*        ws_e   = (float*)((char*)d_ws + E_OFF);
  unsigned int* ws_cnt = (unsigned int*)((char*)d_ws + CNT_OFF);

  ka_fused<<<NPARTS, 256, 0, stream>>>(x, w_in, b_in, w_out, b_out,
                                       ws_C, ws_pc, ws_cnt, outv, ind);
  kb_final<<<256, 256, 0, stream>>>(ws_C, ws_pc, ws_e, ws_cnt, aux);
}

// Round 11
// 42.248 us; speedup vs baseline: 1.2744x; 1.2744x over previous
//
#include <hip/hip_runtime.h>
#include <math.h>

#define NTOK 8192
#define DIMV 512
#define CD 13
#define KSZ 8192
#define NPARTS 512            /* KA blocks == partial-C count               */
#define TPB 16                /* tokens per KA block                        */

/* d_ws layout:
   [0, 16MB)          ws_C   : NPARTS x 8192 partial C
   [+0, +4KB)         ws_pc  : 512 x {cm, pe}
   [+4KB, +1KB)       ws_e   : 256 entropy partials
   [+1KB, +16B)       ws_cnt : done-counter (zeroed by KA each call)        */
#define C_BYTES  ((size_t)NPARTS * KSZ * 4)
#define PC_OFF   C_BYTES
#define E_OFF    (PC_OFF + 4096)
#define CNT_OFF  (E_OFF + 1024)

// ---------------------------------------------------------------------------
// KA: 512 blocks x 256 threads (4 waves), 16 tokens/block (4/wave).
// Lane owns d-slices [4l,4l+4) and [256+4l,260+4l); its 104 w_in values are
// loaded ONCE into registers. Per token: 2 coalesced float4 x-loads, 104 FMA,
// LDS transpose-reduce (f32 partials -> f64 fixed-order sum), ballot index,
// h->LDS. Then: out = sign(h)@w_out+b_out (w_out from L2), factors A/B,
// 8x4-tiled outer product -> ws_C.
// ---------------------------------------------------------------------------
__global__ __launch_bounds__(256) void ka_fused(const float* __restrict__ x,
                                                const float* __restrict__ w_in,
                                                const float* __restrict__ b_in,
                                                const float* __restrict__ w_out,
                                                const float* __restrict__ b_out,
                                                float* __restrict__ ws_C,
                                                float* __restrict__ ws_pc,
                                                unsigned int* __restrict__ ws_cnt,
                                                float* __restrict__ outv,
                                                float* __restrict__ out_ind) {
  __shared__ __align__(16) float pbuf[4][16][68];    // [wave][c(16)][64+pad]
  __shared__ __align__(16) float sh[TPB][16];        // h per token (pad 16)
  __shared__ __align__(16) float sA[TPB][64];        // [tok][khi]
  __shared__ __align__(16) float sB[TPB][128];       // [tok][klo]
  __shared__ float s_cm[4], s_pe[4];
  int t = threadIdx.x;

  if (blockIdx.x == 0 && t == 0) *ws_cnt = 0u;       // reset KB's counter

  int lane = t & 63;
  int wave = t >> 6;          // 0..3
  int rc = lane >> 2;         // channel 0..15 (13 used)
  int q  = lane & 3;          // quarter
  int rrow = (rc < CD) ? rc : 0;

  // ---- w_in rows (4l..4l+3) and (256+4l..256+4l+3) into registers ----
  // wreg[i*13+c] = w_in[row_i][c]; rows 0..3 = 4l+i, rows 4..7 = 256+4l+(i-4)
  float wreg[104];
  {
    const float4* wsrc0 = (const float4*)w_in + (size_t)lane * 13;        // 4l*13/4
    const float4* wsrc1 = (const float4*)w_in + 832 + (size_t)lane * 13;  // (256+4l)*13/4
#pragma unroll
    for (int k = 0; k < 13; ++k) *(float4*)&wreg[k * 4] = wsrc0[k];
#pragma unroll
    for (int k = 0; k < 13; ++k) *(float4*)&wreg[52 + k * 4] = wsrc1[k];
  }
  float bi = b_in[rrow];
  const float* prow = &pbuf[wave][rrow][q * 16];

  float cmacc = 0.f, peacc = 0.f;
  int id2[4];

  // ---------------- token loop: 4 tokens per wave ----------------
#pragma unroll
  for (int it = 0; it < 4; ++it) {
    int tok = wave * 4 + it;
    int n = blockIdx.x * TPB + tok;
    const float4* x4 = (const float4*)(x + (size_t)n * DIMV);
    float4 xv0 = x4[lane];         // d = 4l .. 4l+3
    float4 xv1 = x4[64 + lane];    // d = 256+4l .. 256+4l+3

    float facc[CD];
#pragma unroll
    for (int c = 0; c < CD; ++c) {
      facc[c] = xv0.x * wreg[c]        + xv0.y * wreg[13 + c] +
                xv0.z * wreg[26 + c]   + xv0.w * wreg[39 + c] +
                xv1.x * wreg[52 + c]   + xv1.y * wreg[65 + c] +
                xv1.z * wreg[78 + c]   + xv1.w * wreg[91 + c];
    }
#pragma unroll
    for (int c = 0; c < CD; ++c) pbuf[wave][c][lane] = facc[c];
    // same-wave LDS RAW: ordered by lgkmcnt, no barrier needed
    float4 r0 = *(const float4*)&prow[0];
    float4 r1 = *(const float4*)&prow[4];
    float4 r2 = *(const float4*)&prow[8];
    float4 r3 = *(const float4*)&prow[12];
    double s = (double)r0.x + (double)r0.y + (double)r0.z + (double)r0.w
             + (double)r1.x + (double)r1.y + (double)r1.z + (double)r1.w
             + (double)r2.x + (double)r2.y + (double)r2.z + (double)r2.w
             + (double)r3.x + (double)r3.y + (double)r3.z + (double)r3.w;
    s += __shfl_xor(s, 1, 64);         // combine quarters (deterministic)
    s += __shfl_xor(s, 2, 64);
    double h = s + (double)bi;

    unsigned long long mask = __ballot(h > 0.0);
    int idx = 0;
#pragma unroll
    for (int c = 0; c < CD; ++c)
      idx |= (int)((mask >> (4 * c)) & 1ull) << (12 - c);
    id2[it] = idx;

    if (q == 0 && rc < CD) {
      float hv = (float)h;
      sh[tok][rc] = hv;
      float a = fabsf(hv);
      float d1 = a - 1.f;
      cmacc += d1 * d1;                 // (h - sign(h))^2 == (|h|-1)^2
      float z = 4.f * a;                // binary entropy of sigmoid(4h)
      float e = expf(-z);
      peacc += log1pf(e) + z * e / (1.f + e);
    }
  }

  // lane 0 of each wave gets block partials (zeros elsewhere)
  cmacc += __shfl_xor(cmacc, 1, 64); peacc += __shfl_xor(peacc, 1, 64);
  cmacc += __shfl_xor(cmacc, 2, 64); peacc += __shfl_xor(peacc, 2, 64);
  cmacc += __shfl_xor(cmacc, 4, 64); peacc += __shfl_xor(peacc, 4, 64);
  cmacc += __shfl_xor(cmacc, 8, 64); peacc += __shfl_xor(peacc, 8, 64);
  cmacc += __shfl_xor(cmacc, 16, 64); peacc += __shfl_xor(peacc, 16, 64);
  cmacc += __shfl_xor(cmacc, 32, 64); peacc += __shfl_xor(peacc, 32, 64);
  if (lane == 0) { s_cm[wave] = cmacc; s_pe[wave] = peacc; }

  // ---- out = sign(h) @ w_out + b_out; wave's own 4 tokens, idx in regs ----
  {
    int dpos = lane * 4;
    float4 bo0 = *(const float4*)(b_out + dpos);
    float4 bo1 = *(const float4*)(b_out + dpos + 256);
    float4 o[4][2];
#pragma unroll
    for (int it = 0; it < 4; ++it) { o[it][0] = bo0; o[it][1] = bo1; }
#pragma unroll
    for (int c = 0; c < CD; ++c) {
      const float4 w0 = *(const float4*)&w_out[c * DIMV + dpos];
      const float4 w1 = *(const float4*)&w_out[c * DIMV + dpos + 256];
#pragma unroll
      for (int it = 0; it < 4; ++it) {
        float sgn = ((id2[it] >> (12 - c)) & 1) ? 1.f : -1.f;
        o[it][0].x = fmaf(sgn, w0.x, o[it][0].x);
        o[it][0].y = fmaf(sgn, w0.y, o[it][0].y);
        o[it][0].z = fmaf(sgn, w0.z, o[it][0].z);
        o[it][0].w = fmaf(sgn, w0.w, o[it][0].w);
        o[it][1].x = fmaf(sgn, w1.x, o[it][1].x);
        o[it][1].y = fmaf(sgn, w1.y, o[it][1].y);
        o[it][1].z = fmaf(sgn, w1.z, o[it][1].z);
        o[it][1].w = fmaf(sgn, w1.w, o[it][1].w);
      }
    }
    int n0 = blockIdx.x * TPB + wave * 4;
#pragma unroll
    for (int it = 0; it < 4; ++it) {
      float4* dst = (float4*)(outv + (size_t)(n0 + it) * DIMV);
      dst[lane] = o[it][0];
      dst[lane + 64] = o[it][1];
    }
    if (lane == 0) out_ind[n0 + 0] = (float)id2[0];
    if (lane == 0) out_ind[n0 + 1] = (float)id2[1];
    if (lane == 0) out_ind[n0 + 2] = (float)id2[2];
    if (lane == 0) out_ind[n0 + 3] = (float)id2[3];
  }

  // ---- factors: wave's own 4 tokens (sh written by this wave; no barrier) --
#pragma unroll
  for (int it = 0; it < 4; ++it) {
    int m = wave * 4 + it;
    float4 h0 = *(const float4*)&sh[m][0];
    float4 h1 = *(const float4*)&sh[m][4];
    float4 h2 = *(const float4*)&sh[m][8];
    float4 h3 = *(const float4*)&sh[m][12];
    float hs[CD] = {h0.x, h0.y, h0.z, h0.w, h1.x, h1.y, h1.z, h1.w,
                    h2.x, h2.y, h2.z, h2.w, h3.x};
    float p[CD], qq[CD];
#pragma unroll
    for (int c = 0; c < CD; ++c) {
      float e = expf(-4.f * hs[c]);
      float r = 1.f / (1.f + e);
      p[c] = r;                         // P(bit c = 1)
      qq[c] = e * r;                    // P(bit c = 0)
    }
    float A = ((lane >> 5) & 1) ? p[0] : qq[0];
    A *= ((lane >> 4) & 1) ? p[1] : qq[1];
    A *= ((lane >> 3) & 1) ? p[2] : qq[2];
    A *= ((lane >> 2) & 1) ? p[3] : qq[3];
    A *= ((lane >> 1) & 1) ? p[4] : qq[4];
    A *= (lane & 1) ? p[5] : qq[5];
    sA[m][lane] = A;                    // khi = lane
    float Bb = ((lane >> 5) & 1) ? p[7] : qq[7];
    Bb *= ((lane >> 4) & 1) ? p[8] : qq[8];
    Bb *= ((lane >> 3) & 1) ? p[9] : qq[9];
    Bb *= ((lane >> 2) & 1) ? p[10] : qq[10];
    Bb *= ((lane >> 1) & 1) ? p[11] : qq[11];
    Bb *= (lane & 1) ? p[12] : qq[12];
    sB[m][lane] = qq[6] * Bb;           // klo = lane      (bit6 = 0)
    sB[m][64 + lane] = p[6] * Bb;       // klo = lane + 64 (bit6 = 1)
  }
  __syncthreads();                      // sA/sB (+ s_cm/s_pe) complete

  if (t == 0) {
    float C = s_cm[0] + s_cm[1] + s_cm[2] + s_cm[3];
    float P = s_pe[0] + s_pe[1] + s_pe[2] + s_pe[3];
    ws_pc[blockIdx.x * 2] = C;
    ws_pc[blockIdx.x * 2 + 1] = P;
  }

  // ---- outer product, 8x4 tile: khi in [kh0,kh0+8), klo in [kl0,kl0+4) ----
  int kh0 = (t >> 5) << 3;              // 0,8,..,56
  int kl0 = (t & 31) << 2;              // 0,4,..,124
  float4 acc4[8];
#pragma unroll
  for (int a = 0; a < 8; ++a) acc4[a] = make_float4(0.f, 0.f, 0.f, 0.f);
  for (int m = 0; m < TPB; ++m) {
    float4 bv = *(const float4*)&sB[m][kl0];
    float4 av0 = *(const float4*)&sA[m][kh0];
    float4 av1 = *(const float4*)&sA[m][kh0 + 4];
    float Aa[8] = {av0.x, av0.y, av0.z, av0.w, av1.x, av1.y, av1.z, av1.w};
#pragma unroll
    for (int a = 0; a < 8; ++a) {
      acc4[a].x = fmaf(Aa[a], bv.x, acc4[a].x);
      acc4[a].y = fmaf(Aa[a], bv.y, acc4[a].y);
      acc4[a].z = fmaf(Aa[a], bv.z, acc4[a].z);
      acc4[a].w = fmaf(Aa[a], bv.w, acc4[a].w);
    }
  }
  {
    float* dst = ws_C + (size_t)blockIdx.x * KSZ;
#pragma unroll
    for (int a = 0; a < 8; ++a)
      *(float4*)&dst[(kh0 + a) * 128 + kl0] = acc4[a];   // coalesced rows
  }
}

// ---------------------------------------------------------------------------
// KB: reduce NPARTS partial C's -> 256 entropy partials; the LAST block
// (device atomic counter, zeroed by KA) assembles aux (fixed-order sums).
// ---------------------------------------------------------------------------
__global__ __launch_bounds__(256) void kb_final(const float* __restrict__ ws_C,
                                                const float* __restrict__ ws_pc,
                                                float* __restrict__ ws_e,
                                                unsigned int* __restrict__ ws_cnt,
                                                float* __restrict__ d_aux) {
  __shared__ float red[256];
  __shared__ int s_last;
  int t = threadIdx.x;
  int sl = t & 31, pg = t >> 5;
  int s = blockIdx.x * 32 + sl;
  float a0 = 0.f, a1 = 0.f, a2 = 0.f, a3 = 0.f;
  for (int i = 0; i < 64; i += 4) {
    a0 += ws_C[(size_t)(pg + 8 * (i + 0)) * KSZ + s];
    a1 += ws_C[(size_t)(pg + 8 * (i + 1)) * KSZ + s];
    a2 += ws_C[(size_t)(pg + 8 * (i + 2)) * KSZ + s];
    a3 += ws_C[(size_t)(pg + 8 * (i + 3)) * KSZ + s];
  }
  red[t] = (a0 + a1) + (a2 + a3);
  __syncthreads();
  float contrib = 0.f;
  if (t < 32) {
    float v = red[t];
#pragma unroll
    for (int j = 1; j < 8; ++j) v += red[t + 32 * j];
    float avg = v * (1.f / (float)NTOK);
    contrib = -avg * logf(avg + 1e-5f);
  }
  if (t < 64) {
    contrib += __shfl_xor(contrib, 1, 64);
    contrib += __shfl_xor(contrib, 2, 64);
    contrib += __shfl_xor(contrib, 4, 64);
    contrib += __shfl_xor(contrib, 8, 64);
    contrib += __shfl_xor(contrib, 16, 64);
    if (t == 0) ws_e[blockIdx.x] = contrib;
  }
  if (t == 0) {
    __threadfence();
    unsigned int old = atomicAdd(ws_cnt, 1u);
    s_last = (old == 255u) ? 1 : 0;
  }
  __syncthreads();
  if (s_last) {
    __threadfence();                    // acquire: see all ws_e / ws_pc
    __shared__ float rc[256], rp[256], re[256];
    float cm2 = 0.f, pe2 = 0.f;
    for (int i = t; i < 512; i += 256) {
      cm2 += ws_pc[2 * i];
      pe2 += ws_pc[2 * i + 1];
    }
    rc[t] = cm2; rp[t] = pe2; re[t] = ws_e[t];
    __syncthreads();
    if (t < 64) {
      float C = rc[t] + rc[t + 64] + rc[t + 128] + rc[t + 192];
      float P = rp[t] + rp[t + 64] + rp[t + 128] + rp[t + 192];
      float E = re[t] + re[t + 64] + re[t + 128] + re[t + 192];
      C += __shfl_xor(C, 1, 64); P += __shfl_xor(P, 1, 64); E += __shfl_xor(E, 1, 64);
      C += __shfl_xor(C, 2, 64); P += __shfl_xor(P, 2, 64); E += __shfl_xor(E, 2, 64);
      C += __shfl_xor(C, 4, 64); P += __shfl_xor(P, 4, 64); E += __shfl_xor(E, 4, 64);
      C += __shfl_xor(C, 8, 64); P += __shfl_xor(P, 8, 64); E += __shfl_xor(E, 8, 64);
      C += __shfl_xor(C, 16, 64); P += __shfl_xor(P, 16, 64); E += __shfl_xor(E, 16, 64);
      C += __shfl_xor(C, 32, 64); P += __shfl_xor(P, 32, 64); E += __shfl_xor(E, 32, 64);
      if (t == 0) {
        float commit = C * (1.f / (float)(NTOK * CD));
        float psE = P * (1.f / (float)NTOK);
        d_aux[0] = 0.1f * (psE - E) + 0.25f * commit;
      }
    }
  }
}

extern "C" void kernel_launch(void* const* d_in, const int* in_sizes, int n_in,
                              void* d_out, int out_size, void* d_ws, size_t ws_size,
                              hipStream_t stream) {
  const float* x     = (const float*)d_in[0];
  const float* w_in  = (const float*)d_in[1];
  const float* b_in  = (const float*)d_in[2];
  const float* w_out = (const float*)d_in[3];
  const float* b_out = (const float*)d_in[4];
  // d_in[5] = codebook (unused: codes are the 13-bit sign patterns)

  float* outv = (float*)d_out;                       // [4*2048*512]
  float* ind  = outv + (size_t)NTOK * DIMV;          // [8192] as float
  float* aux  = ind + NTOK;                          // [1]

  float*        ws_C   = (float*)d_ws;
  float*        ws_pc  = (float*)((char*)d_ws + PC_OFF);
  float*        ws_e   = (float*)((char*)d_ws + E_OFF);
  unsigned int* ws_cnt = (unsigned int*)((char*)d_ws + CNT_OFF);

  ka_fused<<<NPARTS, 256, 0, stream>>>(x, w_in, b_in, w_out, b_out,
                                       ws_C, ws_pc, ws_cnt, outv, ind);
  kb_final<<<256, 256, 0, stream>>>(ws_C, ws_pc, ws_e, ws_cnt, aux);
}